// Round 2
// baseline (206.315 us; speedup 1.0000x reference)
//
#include <hip/hip_runtime.h>

typedef unsigned short ushort_t;
typedef __attribute__((ext_vector_type(8))) short short8;   // 8 bf16 (4 VGPRs)
typedef __attribute__((ext_vector_type(4))) short short4v;  // 4 bf16 (8 B)
typedef __attribute__((ext_vector_type(4))) float floatx4;  // 4 fp32 acc

#define DEV static __device__ __forceinline__
#define NEG_BIG (-1e30f)

// 16x16x16 bf16 MFMA (gfx90a-era "_1k" builtin, carried forward to gfx950 —
// v_mfma_f32_16x16x16_bf16 in cdna4_isa.md §10). A-frag k-pattern (k=quad*4+e)
// matches the x32 C/D row pattern (row=quad*4+r) -> swapped-QK^T output feeds
// PV with NO lane exchange. Direct call (no __has_builtin: host pass can't see
// aux-target builtins through __has_builtin but compiles direct calls fine).
#define MFMA16(a, b, c) __builtin_amdgcn_mfma_f32_16x16x16bf16_1k((a), (b), (c), 0, 0, 0)

typedef const __attribute__((address_space(1))) unsigned int* gas_ptr;
typedef __attribute__((address_space(3))) unsigned int* las_ptr;

// async global->LDS, 16B per lane; LDS dest = base + lane*16 (wave-uniform base)
DEV void async16(const ushort_t* g, ushort_t* l) {
    __builtin_amdgcn_global_load_lds((gas_ptr)(const void*)g, (las_ptr)(void*)l, 16, 0, 0);
}

DEV float bf2f(ushort_t u) {
    union { unsigned u; float f; } v; v.u = ((unsigned)u) << 16; return v.f;
}
DEV ushort_t f2bf(float f) {            // RNE — for values feeding long chains
    union { float f; unsigned u; } v; v.f = f;
    unsigned r = v.u + 0x7FFF + ((v.u >> 16) & 1);
    return (ushort_t)(r >> 16);
}
DEV ushort_t f2bf_trunc(float f) {      // 1-op truncation — P / O only (R13)
    union { float f; unsigned u; } v; v.f = f;
    return (ushort_t)(v.u >> 16);
}
DEV float load_bf16_scrub(const ushort_t* p, size_t i) {
    ushort_t u = p[i];
    if (((u >> 7) & 0xFF) == 0xFF) u = 0;
    return bf2f(u);
}
DEV float load_f32_scrub(const ushort_t* p, size_t i) {
    unsigned u = ((const unsigned*)p)[i];
    if (((u >> 23) & 0xFF) == 0xFF) u = 0;
    union { unsigned u; float f; } v; v.u = u; return v.f;
}

// Probe: fp32 vs bf16 raw data (proven in R3/R4). Block-uniform result.
DEV int probe_is_f32(const ushort_t* __restrict__ p) {
    int tid = threadIdx.x + threadIdx.y * blockDim.x;
    int nthr = blockDim.x * blockDim.y;
    __shared__ int cnt;
    if (tid == 0) cnt = 0;
    __syncthreads();
    int weird = 0;
    for (int i = tid; i < 2048; i += nthr) {
        unsigned e = (p[i] >> 7) & 0xFF;
        weird += (e >= 0x90) ? 1 : 0;
    }
#pragma unroll
    for (int off = 32; off; off >>= 1) weird += __shfl_xor(weird, off);
    if ((tid & 63) == 0) atomicAdd(&cnt, weird);
    __syncthreads();
    return cnt > 16;
}

// ----------------------------------------------- fused prep (1 launch) ------
__global__ void prep_kernel(const ushort_t* __restrict__ W0,
                            const ushort_t* __restrict__ W1,
                            const ushort_t* __restrict__ W2,
                            const ushort_t* __restrict__ W3,
                            ushort_t* __restrict__ WTq3,
                            ushort_t* __restrict__ WoT,
                            const ushort_t* __restrict__ x,
                            const ushort_t* __restrict__ g,
                            ushort_t* __restrict__ xn) {
    int is_f32 = probe_is_f32(x);
    int z = blockIdx.z;
    if (z < 4) {
        const ushort_t* W = (z == 0) ? W0 : (z == 1) ? W1 : (z == 2) ? W2 : W3;
        __shared__ ushort_t tile[32][33];
        int tx = threadIdx.x, ty = threadIdx.y;
        int xx = blockIdx.x * 32 + tx;      // n
        int y0 = blockIdx.y * 32;           // k
#pragma unroll
        for (int j = 0; j < 32; j += 8) {
            size_t idx = (size_t)(y0 + ty + j) * 1024 + xx;
            tile[ty + j][tx] = f2bf(is_f32 ? load_f32_scrub(W, idx) : load_bf16_scrub(W, idx));
        }
        __syncthreads();
        int nx = blockIdx.y * 32 + tx;
        ushort_t* dst = (z < 3) ? WTq3 : WoT;
        int ny0 = blockIdx.x * 32 + ((z < 3) ? z * 1024 : 0);
#pragma unroll
        for (int j = 0; j < 32; j += 8)
            dst[(size_t)(ny0 + ty + j) * 1024 + nx] = tile[tx][ty + j];
    } else {
        int row = (z - 4) * 1024 + blockIdx.y * 32 + blockIdx.x;
        int tid = threadIdx.y * 32 + threadIdx.x;
        float vals[4], gv[4];
        size_t base = (size_t)row * 1024 + tid * 4;
#pragma unroll
        for (int i = 0; i < 4; i++) {
            if (is_f32) {
                vals[i] = load_f32_scrub(x, base + i);
                gv[i]   = load_f32_scrub(g, tid * 4 + i);
            } else {
                vals[i] = load_bf16_scrub(x, base + i);
                gv[i]   = load_bf16_scrub(g, tid * 4 + i);
            }
        }
        float ss = vals[0]*vals[0] + vals[1]*vals[1] + vals[2]*vals[2] + vals[3]*vals[3];
#pragma unroll
        for (int off = 32; off > 0; off >>= 1) ss += __shfl_xor(ss, off);
        __shared__ float red[4];
        if ((tid & 63) == 0) red[tid >> 6] = ss;
        __syncthreads();
        ss = red[0] + red[1] + red[2] + red[3];
        float inv = rsqrtf(ss * (1.0f / 1024.0f) + 1e-6f);
#pragma unroll
        for (int i = 0; i < 4; i++)
            xn[base + i] = f2bf(vals[i] * inv * gv[i]);
    }
}

// ------------------------------------------------------- fused QKV GEMM ----
// 128x128 tile, BK=64, COALESCED async staging (R8/R10-verified; R9 proved
// bank conflicts benign / coalescing binding). XCD-region swizzle.
// Epilogue: fast-math RoPE (__sinf/__cosf), q pre-scaled 1/8, packed V scatter.
__global__ __launch_bounds__(256, 4) void gemm_qkv(const ushort_t* __restrict__ A,
                                                   const ushort_t* __restrict__ Bt,
                                                   ushort_t* __restrict__ qb,
                                                   ushort_t* __restrict__ kb,
                                                   ushort_t* __restrict__ vt) {
    const int K = 1024;
    int tid = threadIdx.x;
    int lane = tid & 63, w = tid >> 6;
    int c = lane & 15, quad = lane >> 4;
    int mh = w >> 1, nh = w & 1;
    int lin = blockIdx.y * gridDim.x + blockIdx.x;     // 768 blocks
    int xcd = lin & 7, idx = lin >> 3;
    int bm = ((xcd & 3) * 8 + (idx & 7)) * 128;        // m-block in [0,32)
    int bn = ((xcd >> 2) * 12 + (idx >> 3)) * 128;     // n-block in [0,24)
    int lr = lane >> 2, lq = lane & 3;                 // staging lane map

    __shared__ __align__(16) ushort_t As[16 * 512];    // 16 KB
    __shared__ __align__(16) ushort_t Bs[16 * 512];    // 16 KB

    const floatx4 zero = {0.f, 0.f, 0.f, 0.f};
    floatx4 acc[4][4];
#pragma unroll
    for (int i = 0; i < 4; i++)
#pragma unroll
        for (int j = 0; j < 4; j++) acc[i][j] = zero;

    for (int k0 = 0; k0 < K; k0 += 64) {
        __syncthreads();
#pragma unroll
        for (int ci = 0; ci < 8; ci++) {
            int ch = w * 8 + ci;              // 0..31, wave-uniform
            if (ch < 16) {
                int rg = ch >> 1, kc = ch & 1;
                async16(A + (size_t)(bm + rg * 16 + lr) * K + k0 + kc * 32 + lq * 8,
                        As + ch * 512);
            } else {
                int b2 = ch - 16;
                int rg = b2 >> 1, kc = b2 & 1;
                async16(Bt + (size_t)(bn + rg * 16 + lr) * K + k0 + kc * 32 + lq * 8,
                        Bs + b2 * 512);
            }
        }
        __syncthreads();
#pragma unroll
        for (int kc = 0; kc < 2; kc++) {
            short8 af[4], bf[4];
#pragma unroll
            for (int i = 0; i < 4; i++)
                af[i] = *(const short8*)(As + ((mh * 4 + i) * 2 + kc) * 512 + c * 32 + quad * 8);
#pragma unroll
            for (int j = 0; j < 4; j++)
                bf[j] = *(const short8*)(Bs + ((nh * 4 + j) * 2 + kc) * 512 + c * 32 + quad * 8);
#pragma unroll
            for (int i = 0; i < 4; i++)
#pragma unroll
                for (int j = 0; j < 4; j++)
                    acc[i][j] = __builtin_amdgcn_mfma_f32_16x16x32_bf16(af[i], bf[j], acc[i][j], 0, 0, 0);
        }
    }

    int proj = bn >> 10;                 // 0=q, 1=k, 2=v (blocks never straddle)
    int n0 = (bn & 1023) + nh * 64;
    if (proj < 2) {                      // RoPE: d = j*16+c, pairs (j, j+2)
        float th0 = exp2f((float)c * (-19.931568569324174f / 32.0f));
        float th1 = exp2f((float)(16 + c) * (-19.931568569324174f / 32.0f));
        float scale = (proj == 0) ? 0.125f : 1.0f;
#pragma unroll
        for (int i = 0; i < 4; i++)
#pragma unroll
            for (int r = 0; r < 4; r++) {
                int s = (bm + mh * 64 + i * 16 + quad * 4 + r) & 2047;
                float a0 = (float)s * th0, a1 = (float)s * th1;
                float sn0 = __sinf(a0), cs0 = __cosf(a0);
                float sn1 = __sinf(a1), cs1 = __cosf(a1);
                float x1a = acc[i][0][r], x2a = acc[i][2][r];
                acc[i][0][r] = (x1a * cs0 - x2a * sn0) * scale;
                acc[i][2][r] = (x1a * sn0 + x2a * cs0) * scale;
                float x1b = acc[i][1][r], x2b = acc[i][3][r];
                acc[i][1][r] = (x1b * cs1 - x2b * sn1) * scale;
                acc[i][3][r] = (x1b * sn1 + x2b * cs1) * scale;
            }
        ushort_t* dst = (proj == 0) ? qb : kb;
#pragma unroll
        for (int i = 0; i < 4; i++)
#pragma unroll
            for (int j = 0; j < 4; j++)
#pragma unroll
                for (int r = 0; r < 4; r++) {
                    int row = bm + mh * 64 + i * 16 + quad * 4 + r;
                    dst[(size_t)row * 1024 + n0 + j * 16 + c] = f2bf(acc[i][j][r]);
                }
    } else {                             // V: packed 8-B scatter (4 consecutive s)
#pragma unroll
        for (int i = 0; i < 4; i++) {
            int row0 = bm + mh * 64 + i * 16 + quad * 4;
            int b = row0 >> 11, s0v = row0 & 2047;
#pragma unroll
            for (int j = 0; j < 4; j++) {
                int col = n0 + j * 16 + c;
                int hh = col >> 6, dh = col & 63;
                short4v pk;
#pragma unroll
                for (int r = 0; r < 4; r++) pk[r] = (short)f2bf(acc[i][j][r]);
                *(short4v*)(vt + (size_t)((b * 16 + hh) * 64 + dh) * 2048 + s0v) = pk;
            }
        }
    }
}

// ----------------------------------------------------- output projection ---
__global__ __launch_bounds__(256, 4) void gemm_out(const ushort_t* __restrict__ A,
                                                   const ushort_t* __restrict__ Bt,
                                                   float* __restrict__ C) {
    const int K = 1024, N = 1024;
    int tid = threadIdx.x;
    int lane = tid & 63, w = tid >> 6;
    int c = lane & 15, quad = lane >> 4;
    int mh = w >> 1, nh = w & 1;
    int lin = blockIdx.y * gridDim.x + blockIdx.x;     // 512 blocks
    int xcd = lin & 7, idx = lin >> 3;
    int bm = ((xcd & 3) * 8 + (idx & 7)) * 128;
    int bn = ((xcd >> 2) * 8 + (idx >> 3)) * 64;
    int lr = lane >> 2, lq = lane & 3;

    __shared__ __align__(16) ushort_t As[16 * 512];
    __shared__ __align__(16) ushort_t Bs[8 * 512];

    const floatx4 zero = {0.f, 0.f, 0.f, 0.f};
    floatx4 acc[4][2];
#pragma unroll
    for (int i = 0; i < 4; i++)
#pragma unroll
        for (int j = 0; j < 2; j++) acc[i][j] = zero;

    for (int k0 = 0; k0 < K; k0 += 64) {
        __syncthreads();
#pragma unroll
        for (int ci = 0; ci < 6; ci++) {
            int ch = w * 6 + ci;              // 0..23, wave-uniform
            if (ch < 16) {
                int rg = ch >> 1, kc = ch & 1;
                async16(A + (size_t)(bm + rg * 16 + lr) * K + k0 + kc * 32 + lq * 8,
                        As + ch * 512);
            } else {
                int b2 = ch - 16;
                int rg = b2 >> 1, kc = b2 & 1;
                async16(Bt + (size_t)(bn + rg * 16 + lr) * K + k0 + kc * 32 + lq * 8,
                        Bs + b2 * 512);
            }
        }
        __syncthreads();
#pragma unroll
        for (int kc = 0; kc < 2; kc++) {
            short8 af[4], bf[2];
#pragma unroll
            for (int i = 0; i < 4; i++)
                af[i] = *(const short8*)(As + ((mh * 4 + i) * 2 + kc) * 512 + c * 32 + quad * 8);
#pragma unroll
            for (int j = 0; j < 2; j++)
                bf[j] = *(const short8*)(Bs + ((nh * 2 + j) * 2 + kc) * 512 + c * 32 + quad * 8);
#pragma unroll
            for (int i = 0; i < 4; i++)
#pragma unroll
                for (int j = 0; j < 2; j++)
                    acc[i][j] = __builtin_amdgcn_mfma_f32_16x16x32_bf16(af[i], bf[j], acc[i][j], 0, 0, 0);
        }
    }
#pragma unroll
    for (int i = 0; i < 4; i++)
#pragma unroll
        for (int j = 0; j < 2; j++)
#pragma unroll
            for (int r = 0; r < 4; r++) {
                int row = bm + mh * 64 + i * 16 + quad * 4 + r;
                int col = bn + nh * 32 + j * 16 + c;
                C[(size_t)row * N + col] = acc[i][j][r];
            }
}

// -------------------------------------------------------------- attention ---
// R15 (= R14 with MFMA16 builtin-name fix): swapped QK^T — compute mfma(K, Q)
// so S^T lands with row=quad*4+r per lane; that row pattern IS the A-fragment
// k-pattern (k=quad*4+e) of mfma 16x16x16 bf16, so exp(S) feeds PV straight
// from registers: NO Ps LDS buffer, no cross-lane exchange. PV = 16x mfma16
// (same FLOPs; MFMA pipe was 14% busy — issue slots are free).
// V LDS: 8-short blocks rotated per row ((blk+row)&3) via pre-swizzled GLOBAL
// source (linear LDS dest — global_load_lds rule), so PV's ds_read_b64
// spreads banks. Verified inverse: staged slot (lr=c, lq=(nt*2+(quad>>1)+c)&3,
// e=(quad&1)*4+e') == read voffA/voffB (+512 for hf=1).
// LDS 41984 -> 32768 B  =>  5 blocks/CU (was 3), 20 waves/CU.
__global__ __launch_bounds__(256, 5) void attn_kernel(const ushort_t* __restrict__ q,
                                                      const ushort_t* __restrict__ k,
                                                      const ushort_t* __restrict__ vt,
                                                      ushort_t* __restrict__ o) {
    int tid = threadIdx.x;
    int lane = tid & 63, w = tid >> 6;
    int c = lane & 15, quad = lane >> 4;
    int bh = blockIdx.x;
    int b = bh >> 4, h = bh & 15;
    int qt = 31 - (int)blockIdx.y;      // heaviest (qt=31) first
    int lr = lane >> 2, lq = lane & 3;
    int vb = (lq - lr) & 3;             // V stage-side block rotation
    const ushort_t* qb  = q + (size_t)b * 2048 * 1024 + h * 64;
    const ushort_t* kbp = k + (size_t)b * 2048 * 1024 + h * 64;
    const ushort_t* vtb = vt + (size_t)(b * 16 + h) * 64 * 2048;
    ushort_t* ob = o + (size_t)b * 2048 * 1024 + h * 64;

    __shared__ __align__(16) ushort_t Ks[2][8 * 512];   // 16 KB
    __shared__ __align__(16) ushort_t Vs[2][8 * 512];   // 16 KB

    const floatx4 zero = {0.f, 0.f, 0.f, 0.f};

    int t0b = qt * 64;
    int t0w = t0b + w * 16;
    int ntile = qt + 1;

    // Q rows for this wave; used as the MFMA **B** operand (same registers —
    // A-frag and B-frag share the lane->(idx16,k) map, so no load change).
    const ushort_t* qrow = qb + (size_t)(t0w + c) * 1024;
    short8 aq0 = *(const short8*)(qrow + quad * 8);
    short8 aq1 = *(const short8*)(qrow + 32 + quad * 8);

    // PV read offsets (read-side inverse of the stage rotation), in shorts.
    int voffA = c * 32 + (((quad >> 1) + c) & 3) * 8 + (quad & 1) * 4;        // nt=0 (or 2 at +512)
    int voffB = c * 32 + (((quad >> 1) + 2 + c) & 3) * 8 + (quad & 1) * 4;    // nt=1 (or 3 at +512)

    float l_sum = 0.f;
    floatx4 oacc[4];
#pragma unroll
    for (int dt = 0; dt < 4; dt++) oacc[dt] = zero;

    // prologue: stage tile 0 into buffer 0
#pragma unroll
    for (int ci = 0; ci < 4; ci++) {
        int ch = w * 4 + ci;
        if (ch < 8) {
            int nt = ch >> 1, hf = ch & 1;
            async16(kbp + (size_t)(nt * 16 + lr) * 1024 + hf * 32 + lq * 8,
                    Ks[0] + ch * 512);
        } else {
            int dt = (ch - 8) >> 1, hf = ch & 1;
            async16(vtb + (size_t)(dt * 16 + lr) * 2048 + hf * 32 + vb * 8,
                    Vs[0] + (ch - 8) * 512);
        }
    }

    for (int kt = 0; kt < ntile; kt++) {
        __syncthreads();    // drains tile kt's loads
        int cur = kt & 1;
        if (kt + 1 < ntile) {
            int s1 = (kt + 1) * 64;
            int nxt = cur ^ 1;
#pragma unroll
            for (int ci = 0; ci < 4; ci++) {
                int ch = w * 4 + ci;
                if (ch < 8) {
                    int nt = ch >> 1, hf = ch & 1;
                    async16(kbp + (size_t)(s1 + nt * 16 + lr) * 1024 + hf * 32 + lq * 8,
                            Ks[nxt] + ch * 512);
                } else {
                    int dt = (ch - 8) >> 1, hf = ch & 1;
                    async16(vtb + (size_t)(dt * 16 + lr) * 2048 + s1 + hf * 32 + vb * 8,
                            Vs[nxt] + (ch - 8) * 512);
                }
            }
        }
        int s0 = kt * 64;

        // ---- QK^T swapped: sacc[nt][r] = S[t0w + c][s0 + nt*16 + quad*4 + r]
        floatx4 sacc[4];
#pragma unroll
        for (int nt = 0; nt < 4; nt++) sacc[nt] = zero;
        __builtin_amdgcn_s_setprio(1);
#pragma unroll
        for (int nt = 0; nt < 4; nt++) {
            short8 k0f = *(const short8*)(Ks[cur] + nt * 1024 + c * 32 + quad * 8);
            short8 k1f = *(const short8*)(Ks[cur] + nt * 1024 + 512 + c * 32 + quad * 8);
            sacc[nt] = __builtin_amdgcn_mfma_f32_16x16x32_bf16(k0f, aq0, sacc[nt], 0, 0, 0);
            sacc[nt] = __builtin_amdgcn_mfma_f32_16x16x32_bf16(k1f, aq1, sacc[nt], 0, 0, 0);
        }
        __builtin_amdgcn_s_setprio(0);

        // ---- softmax (whole row lives in this lane; no LDS round-trip)
        short4v pa[4];
        float ps = 0.f;
        if (kt == ntile - 1) {           // diagonal tile: causal mask
            int t = t0w + c;
#pragma unroll
            for (int nt = 0; nt < 4; nt++) {
                float pn = 0.f;
#pragma unroll
                for (int r = 0; r < 4; r++) {
                    int s = s0 + nt * 16 + quad * 4 + r;
                    float e = __expf((s > t) ? NEG_BIG : sacc[nt][r]);
                    pn += e;
                    pa[nt][r] = (short)f2bf_trunc(e);
                }
                ps += pn;
            }
        } else {
#pragma unroll
            for (int nt = 0; nt < 4; nt++) {
                float pn = 0.f;
#pragma unroll
                for (int r = 0; r < 4; r++) {
                    float e = __expf(sacc[nt][r]);
                    pn += e;
                    pa[nt][r] = (short)f2bf_trunc(e);
                }
                ps += pn;
            }
        }
        l_sum += ps;

        // ---- PV: A = pa[nt] (k=quad*4+e matches S^T row pattern), B = V^T
        __builtin_amdgcn_s_setprio(1);
#pragma unroll
        for (int dt = 0; dt < 4; dt++) {
            const ushort_t* vbase = Vs[cur] + dt * 1024;
            short4v bv0 = *(const short4v*)(vbase + voffA);
            short4v bv1 = *(const short4v*)(vbase + voffB);
            short4v bv2 = *(const short4v*)(vbase + 512 + voffA);
            short4v bv3 = *(const short4v*)(vbase + 512 + voffB);
            oacc[dt] = MFMA16(pa[0], bv0, oacc[dt]);
            oacc[dt] = MFMA16(pa[1], bv1, oacc[dt]);
            oacc[dt] = MFMA16(pa[2], bv2, oacc[dt]);
            oacc[dt] = MFMA16(pa[3], bv3, oacc[dt]);
        }
        __builtin_amdgcn_s_setprio(0);
    }

    // row sum for q-row t0w+c lives at lanes {c, c+16, c+32, c+48}
    float l = l_sum;
    l += __shfl_xor(l, 16);
    l += __shfl_xor(l, 32);
    float linv0 = 1.0f / l;              // valid for row t0w + c
    float linv[4];
#pragma unroll
    for (int r = 0; r < 4; r++) linv[r] = __shfl(linv0, quad * 4 + r);

#pragma unroll
    for (int dt = 0; dt < 4; dt++)
#pragma unroll
        for (int r = 0; r < 4; r++) {
            int t = t0w + quad * 4 + r;
            ob[(size_t)t * 1024 + dt * 16 + c] = f2bf_trunc(oacc[dt][r] * linv[r]);
        }
}

// ------------------------------------------------------------------ launch ---
extern "C" void kernel_launch(void* const* d_in, const int* in_sizes, int n_in,
                              void* d_out, int out_size, void* d_ws, size_t ws_size,
                              hipStream_t stream) {
    const ushort_t* x  = (const ushort_t*)d_in[0];
    const ushort_t* g  = (const ushort_t*)d_in[1];
    const ushort_t* Wq = (const ushort_t*)d_in[2];
    const ushort_t* Wk = (const ushort_t*)d_in[3];
    const ushort_t* Wv = (const ushort_t*)d_in[4];
    const ushort_t* Wo = (const ushort_t*)d_in[5];

    char* ws = (char*)d_ws;
    const size_t MB = 1ull << 20;
    ushort_t* xn   = (ushort_t*)(ws);            // 8 MB (reused as attn out)
    ushort_t* qb   = (ushort_t*)(ws + 8 * MB);   // 8 MB
    ushort_t* kb   = (ushort_t*)(ws + 16 * MB);  // 8 MB
    ushort_t* vt   = (ushort_t*)(ws + 24 * MB);  // 8 MB ([b,h,dh,s])
    ushort_t* WTq3 = (ushort_t*)(ws + 32 * MB);  // 6 MB (q|k|v transposed)
    ushort_t* WoT  = (ushort_t*)(ws + 38 * MB);  // 2 MB  -> total 40 MB
    ushort_t* at   = xn;

    prep_kernel<<<dim3(32, 32, 8), dim3(32, 8), 0, stream>>>(Wq, Wk, Wv, Wo, WTq3, WoT, x, g, xn);

    gemm_qkv<<<dim3(24, 32), 256, 0, stream>>>(xn, WTq3, qb, kb, vt);

    attn_kernel<<<dim3(32, 32), 256, 0, stream>>>(qb, kb, vt, at);

    gemm_out<<<dim3(16, 32), 256, 0, stream>>>(at, WoT, (float*)d_out);
}

// Round 3
// 185.859 us; speedup vs baseline: 1.1101x; 1.1101x over previous
//
#include <hip/hip_runtime.h>

typedef unsigned short ushort_t;
typedef __attribute__((ext_vector_type(8))) short short8;   // 8 bf16 (4 VGPRs)
typedef __attribute__((ext_vector_type(4))) short short4v;  // 4 bf16 (8 B)
typedef __attribute__((ext_vector_type(4))) float floatx4;  // 4 fp32 acc

#define DEV static __device__ __forceinline__
#define NEG_BIG (-1e30f)

typedef const __attribute__((address_space(1))) unsigned int* gas_ptr;
typedef __attribute__((address_space(3))) unsigned int* las_ptr;

// async global->LDS, 16B per lane; LDS dest = base + lane*16 (wave-uniform base)
DEV void async16(const ushort_t* g, ushort_t* l) {
    __builtin_amdgcn_global_load_lds((gas_ptr)(const void*)g, (las_ptr)(void*)l, 16, 0, 0);
}

DEV float bf2f(ushort_t u) {
    union { unsigned u; float f; } v; v.u = ((unsigned)u) << 16; return v.f;
}
DEV ushort_t f2bf(float f) {            // RNE — for values feeding long chains
    union { float f; unsigned u; } v; v.f = f;
    unsigned r = v.u + 0x7FFF + ((v.u >> 16) & 1);
    return (ushort_t)(r >> 16);
}
DEV ushort_t f2bf_trunc(float f) {      // 1-op truncation — P / O only (R13)
    union { float f; unsigned u; } v; v.f = f;
    return (ushort_t)(v.u >> 16);
}
DEV float load_bf16_scrub(const ushort_t* p, size_t i) {
    ushort_t u = p[i];
    if (((u >> 7) & 0xFF) == 0xFF) u = 0;
    return bf2f(u);
}
DEV float load_f32_scrub(const ushort_t* p, size_t i) {
    unsigned u = ((const unsigned*)p)[i];
    if (((u >> 23) & 0xFF) == 0xFF) u = 0;
    union { unsigned u; float f; } v; v.u = u; return v.f;
}

// Probe: fp32 vs bf16 raw data (proven in R3/R4). Block-uniform result.
DEV int probe_is_f32(const ushort_t* __restrict__ p) {
    int tid = threadIdx.x + threadIdx.y * blockDim.x;
    int nthr = blockDim.x * blockDim.y;
    __shared__ int cnt;
    if (tid == 0) cnt = 0;
    __syncthreads();
    int weird = 0;
    for (int i = tid; i < 2048; i += nthr) {
        unsigned e = (p[i] >> 7) & 0xFF;
        weird += (e >= 0x90) ? 1 : 0;
    }
#pragma unroll
    for (int off = 32; off; off >>= 1) weird += __shfl_xor(weird, off);
    if ((tid & 63) == 0) atomicAdd(&cnt, weird);
    __syncthreads();
    return cnt > 16;
}

// ----------------------------------------------- fused prep (1 launch) ------
__global__ void prep_kernel(const ushort_t* __restrict__ W0,
                            const ushort_t* __restrict__ W1,
                            const ushort_t* __restrict__ W2,
                            const ushort_t* __restrict__ W3,
                            ushort_t* __restrict__ WTq3,
                            ushort_t* __restrict__ WoT,
                            const ushort_t* __restrict__ x,
                            const ushort_t* __restrict__ g,
                            ushort_t* __restrict__ xn) {
    int is_f32 = probe_is_f32(x);
    int z = blockIdx.z;
    if (z < 4) {
        const ushort_t* W = (z == 0) ? W0 : (z == 1) ? W1 : (z == 2) ? W2 : W3;
        __shared__ ushort_t tile[32][33];
        int tx = threadIdx.x, ty = threadIdx.y;
        int xx = blockIdx.x * 32 + tx;      // n
        int y0 = blockIdx.y * 32;           // k
#pragma unroll
        for (int j = 0; j < 32; j += 8) {
            size_t idx = (size_t)(y0 + ty + j) * 1024 + xx;
            tile[ty + j][tx] = f2bf(is_f32 ? load_f32_scrub(W, idx) : load_bf16_scrub(W, idx));
        }
        __syncthreads();
        int nx = blockIdx.y * 32 + tx;
        ushort_t* dst = (z < 3) ? WTq3 : WoT;
        int ny0 = blockIdx.x * 32 + ((z < 3) ? z * 1024 : 0);
#pragma unroll
        for (int j = 0; j < 32; j += 8)
            dst[(size_t)(ny0 + ty + j) * 1024 + nx] = tile[tx][ty + j];
    } else {
        int row = (z - 4) * 1024 + blockIdx.y * 32 + blockIdx.x;
        int tid = threadIdx.y * 32 + threadIdx.x;
        float vals[4], gv[4];
        size_t base = (size_t)row * 1024 + tid * 4;
#pragma unroll
        for (int i = 0; i < 4; i++) {
            if (is_f32) {
                vals[i] = load_f32_scrub(x, base + i);
                gv[i]   = load_f32_scrub(g, tid * 4 + i);
            } else {
                vals[i] = load_bf16_scrub(x, base + i);
                gv[i]   = load_bf16_scrub(g, tid * 4 + i);
            }
        }
        float ss = vals[0]*vals[0] + vals[1]*vals[1] + vals[2]*vals[2] + vals[3]*vals[3];
#pragma unroll
        for (int off = 32; off > 0; off >>= 1) ss += __shfl_xor(ss, off);
        __shared__ float red[4];
        if ((tid & 63) == 0) red[tid >> 6] = ss;
        __syncthreads();
        ss = red[0] + red[1] + red[2] + red[3];
        float inv = rsqrtf(ss * (1.0f / 1024.0f) + 1e-6f);
#pragma unroll
        for (int i = 0; i < 4; i++)
            xn[base + i] = f2bf(vals[i] * inv * gv[i]);
    }
}

// ------------------------------------------------------- fused QKV GEMM ----
// 128x128 tile, BK=64, COALESCED async staging (R8/R10-verified; R9 proved
// bank conflicts benign / coalescing binding). XCD-region swizzle.
// Epilogue: fast-math RoPE (__sinf/__cosf), q pre-scaled 1/8, packed V scatter.
__global__ __launch_bounds__(256, 4) void gemm_qkv(const ushort_t* __restrict__ A,
                                                   const ushort_t* __restrict__ Bt,
                                                   ushort_t* __restrict__ qb,
                                                   ushort_t* __restrict__ kb,
                                                   ushort_t* __restrict__ vt) {
    const int K = 1024;
    int tid = threadIdx.x;
    int lane = tid & 63, w = tid >> 6;
    int c = lane & 15, quad = lane >> 4;
    int mh = w >> 1, nh = w & 1;
    int lin = blockIdx.y * gridDim.x + blockIdx.x;     // 768 blocks
    int xcd = lin & 7, idx = lin >> 3;
    int bm = ((xcd & 3) * 8 + (idx & 7)) * 128;        // m-block in [0,32)
    int bn = ((xcd >> 2) * 12 + (idx >> 3)) * 128;     // n-block in [0,24)
    int lr = lane >> 2, lq = lane & 3;                 // staging lane map

    __shared__ __align__(16) ushort_t As[16 * 512];    // 16 KB
    __shared__ __align__(16) ushort_t Bs[16 * 512];    // 16 KB

    const floatx4 zero = {0.f, 0.f, 0.f, 0.f};
    floatx4 acc[4][4];
#pragma unroll
    for (int i = 0; i < 4; i++)
#pragma unroll
        for (int j = 0; j < 4; j++) acc[i][j] = zero;

    for (int k0 = 0; k0 < K; k0 += 64) {
        __syncthreads();
#pragma unroll
        for (int ci = 0; ci < 8; ci++) {
            int ch = w * 8 + ci;              // 0..31, wave-uniform
            if (ch < 16) {
                int rg = ch >> 1, kc = ch & 1;
                async16(A + (size_t)(bm + rg * 16 + lr) * K + k0 + kc * 32 + lq * 8,
                        As + ch * 512);
            } else {
                int b2 = ch - 16;
                int rg = b2 >> 1, kc = b2 & 1;
                async16(Bt + (size_t)(bn + rg * 16 + lr) * K + k0 + kc * 32 + lq * 8,
                        Bs + b2 * 512);
            }
        }
        __syncthreads();
#pragma unroll
        for (int kc = 0; kc < 2; kc++) {
            short8 af[4], bf[4];
#pragma unroll
            for (int i = 0; i < 4; i++)
                af[i] = *(const short8*)(As + ((mh * 4 + i) * 2 + kc) * 512 + c * 32 + quad * 8);
#pragma unroll
            for (int j = 0; j < 4; j++)
                bf[j] = *(const short8*)(Bs + ((nh * 4 + j) * 2 + kc) * 512 + c * 32 + quad * 8);
#pragma unroll
            for (int i = 0; i < 4; i++)
#pragma unroll
                for (int j = 0; j < 4; j++)
                    acc[i][j] = __builtin_amdgcn_mfma_f32_16x16x32_bf16(af[i], bf[j], acc[i][j], 0, 0, 0);
        }
    }

    int proj = bn >> 10;                 // 0=q, 1=k, 2=v (blocks never straddle)
    int n0 = (bn & 1023) + nh * 64;
    if (proj < 2) {                      // RoPE: d = j*16+c, pairs (j, j+2)
        float th0 = exp2f((float)c * (-19.931568569324174f / 32.0f));
        float th1 = exp2f((float)(16 + c) * (-19.931568569324174f / 32.0f));
        float scale = (proj == 0) ? 0.125f : 1.0f;
#pragma unroll
        for (int i = 0; i < 4; i++)
#pragma unroll
            for (int r = 0; r < 4; r++) {
                int s = (bm + mh * 64 + i * 16 + quad * 4 + r) & 2047;
                float a0 = (float)s * th0, a1 = (float)s * th1;
                float sn0 = __sinf(a0), cs0 = __cosf(a0);
                float sn1 = __sinf(a1), cs1 = __cosf(a1);
                float x1a = acc[i][0][r], x2a = acc[i][2][r];
                acc[i][0][r] = (x1a * cs0 - x2a * sn0) * scale;
                acc[i][2][r] = (x1a * sn0 + x2a * cs0) * scale;
                float x1b = acc[i][1][r], x2b = acc[i][3][r];
                acc[i][1][r] = (x1b * cs1 - x2b * sn1) * scale;
                acc[i][3][r] = (x1b * sn1 + x2b * cs1) * scale;
            }
        ushort_t* dst = (proj == 0) ? qb : kb;
#pragma unroll
        for (int i = 0; i < 4; i++)
#pragma unroll
            for (int j = 0; j < 4; j++)
#pragma unroll
                for (int r = 0; r < 4; r++) {
                    int row = bm + mh * 64 + i * 16 + quad * 4 + r;
                    dst[(size_t)row * 1024 + n0 + j * 16 + c] = f2bf(acc[i][j][r]);
                }
    } else {                             // V: packed 8-B scatter (4 consecutive s)
#pragma unroll
        for (int i = 0; i < 4; i++) {
            int row0 = bm + mh * 64 + i * 16 + quad * 4;
            int b = row0 >> 11, s0v = row0 & 2047;
#pragma unroll
            for (int j = 0; j < 4; j++) {
                int col = n0 + j * 16 + c;
                int hh = col >> 6, dh = col & 63;
                short4v pk;
#pragma unroll
                for (int r = 0; r < 4; r++) pk[r] = (short)f2bf(acc[i][j][r]);
                *(short4v*)(vt + (size_t)((b * 16 + hh) * 64 + dh) * 2048 + s0v) = pk;
            }
        }
    }
}

// ----------------------------------------------------- output projection ---
__global__ __launch_bounds__(256, 4) void gemm_out(const ushort_t* __restrict__ A,
                                                   const ushort_t* __restrict__ Bt,
                                                   float* __restrict__ C) {
    const int K = 1024, N = 1024;
    int tid = threadIdx.x;
    int lane = tid & 63, w = tid >> 6;
    int c = lane & 15, quad = lane >> 4;
    int mh = w >> 1, nh = w & 1;
    int lin = blockIdx.y * gridDim.x + blockIdx.x;     // 512 blocks
    int xcd = lin & 7, idx = lin >> 3;
    int bm = ((xcd & 3) * 8 + (idx & 7)) * 128;
    int bn = ((xcd >> 2) * 8 + (idx >> 3)) * 64;
    int lr = lane >> 2, lq = lane & 3;

    __shared__ __align__(16) ushort_t As[16 * 512];
    __shared__ __align__(16) ushort_t Bs[8 * 512];

    const floatx4 zero = {0.f, 0.f, 0.f, 0.f};
    floatx4 acc[4][2];
#pragma unroll
    for (int i = 0; i < 4; i++)
#pragma unroll
        for (int j = 0; j < 2; j++) acc[i][j] = zero;

    for (int k0 = 0; k0 < K; k0 += 64) {
        __syncthreads();
#pragma unroll
        for (int ci = 0; ci < 6; ci++) {
            int ch = w * 6 + ci;              // 0..23, wave-uniform
            if (ch < 16) {
                int rg = ch >> 1, kc = ch & 1;
                async16(A + (size_t)(bm + rg * 16 + lr) * K + k0 + kc * 32 + lq * 8,
                        As + ch * 512);
            } else {
                int b2 = ch - 16;
                int rg = b2 >> 1, kc = b2 & 1;
                async16(Bt + (size_t)(bn + rg * 16 + lr) * K + k0 + kc * 32 + lq * 8,
                        Bs + b2 * 512);
            }
        }
        __syncthreads();
#pragma unroll
        for (int kc = 0; kc < 2; kc++) {
            short8 af[4], bf[2];
#pragma unroll
            for (int i = 0; i < 4; i++)
                af[i] = *(const short8*)(As + ((mh * 4 + i) * 2 + kc) * 512 + c * 32 + quad * 8);
#pragma unroll
            for (int j = 0; j < 2; j++)
                bf[j] = *(const short8*)(Bs + ((nh * 2 + j) * 2 + kc) * 512 + c * 32 + quad * 8);
#pragma unroll
            for (int i = 0; i < 4; i++)
#pragma unroll
                for (int j = 0; j < 2; j++)
                    acc[i][j] = __builtin_amdgcn_mfma_f32_16x16x32_bf16(af[i], bf[j], acc[i][j], 0, 0, 0);
        }
    }
#pragma unroll
    for (int i = 0; i < 4; i++)
#pragma unroll
        for (int j = 0; j < 2; j++)
#pragma unroll
            for (int r = 0; r < 4; r++) {
                int row = bm + mh * 64 + i * 16 + quad * 4 + r;
                int col = bn + nh * 32 + j * 16 + c;
                C[(size_t)row * N + col] = acc[i][j][r];
            }
}

// -------------------------------------------------------------- attention ---
// R16 = R13 structure (verified 46.1µs) with ONE delta: Ps[64][72] (9216 B,
// pad-based) -> Ps[64][64] XOR-swizzled (8192 B). Swizzle: short-index
// ^ ((row&7)<<3), i.e. byte ^ ((row&7)<<4), applied AFTER the full
// row*64+col addition on BOTH write and read paths (layout-closed).
// LDS: 2*16384 (K/V dbuf) + 8192 = 40960 B => 4 blocks/CU exactly
// (4 x 40960 = 160 KiB) matching the 1024-block grid: all blocks resident
// from t=0, kernel time ~= longest block, not longest CU queue.
// Swizzle also spreads P writes (<=2-way, free) and makes P b128 reads
// 8-start like the K reads (conflict-free in the b128 sense).
__global__ __launch_bounds__(256) void attn_kernel(const ushort_t* __restrict__ q,
                                                   const ushort_t* __restrict__ k,
                                                   const ushort_t* __restrict__ vt,
                                                   ushort_t* __restrict__ o) {
    int tid = threadIdx.x;
    int lane = tid & 63, w = tid >> 6;
    int c = lane & 15, quad = lane >> 4;
    int bh = blockIdx.x;
    int b = bh >> 4, h = bh & 15;
    int qt = 31 - (int)blockIdx.y;      // heaviest (qt=31) first
    int lr = lane >> 2, lq = lane & 3;
    const ushort_t* qb  = q + (size_t)b * 2048 * 1024 + h * 64;
    const ushort_t* kbp = k + (size_t)b * 2048 * 1024 + h * 64;
    const ushort_t* vtb = vt + (size_t)(b * 16 + h) * 64 * 2048;
    ushort_t* ob = o + (size_t)b * 2048 * 1024 + h * 64;

    __shared__ __align__(16) ushort_t Ks[2][8 * 512];   // 16 KB
    __shared__ __align__(16) ushort_t Vs[2][8 * 512];   // 16 KB
    __shared__ __align__(16) ushort_t Ps[64 * 64];      // 8 KB, XOR-swizzled

    const floatx4 zero = {0.f, 0.f, 0.f, 0.f};

    int t0b = qt * 64;
    int t0w = t0b + w * 16;
    int ntile = qt + 1;

    const ushort_t* qrow = qb + (size_t)(t0w + c) * 1024;
    short8 aq0 = *(const short8*)(qrow + quad * 8);
    short8 aq1 = *(const short8*)(qrow + 32 + quad * 8);

    float l_part[4];
    floatx4 oacc[4];
#pragma unroll
    for (int r = 0; r < 4; r++) l_part[r] = 0.f;
#pragma unroll
    for (int dt = 0; dt < 4; dt++) oacc[dt] = zero;

    // prologue: stage tile 0 into buffer 0
#pragma unroll
    for (int ci = 0; ci < 4; ci++) {
        int ch = w * 4 + ci;
        if (ch < 8) {
            int nt = ch >> 1, hf = ch & 1;
            async16(kbp + (size_t)(nt * 16 + lr) * 1024 + hf * 32 + lq * 8,
                    Ks[0] + ch * 512);
        } else {
            int dt = (ch - 8) >> 1, hf = ch & 1;
            async16(vtb + (size_t)(dt * 16 + lr) * 2048 + hf * 32 + lq * 8,
                    Vs[0] + (ch - 8) * 512);
        }
    }

    for (int kt = 0; kt < ntile; kt++) {
        __syncthreads();    // drains tile kt's loads
        int cur = kt & 1;
        if (kt + 1 < ntile) {
            int s1 = (kt + 1) * 64;
            int nxt = cur ^ 1;
#pragma unroll
            for (int ci = 0; ci < 4; ci++) {
                int ch = w * 4 + ci;
                if (ch < 8) {
                    int nt = ch >> 1, hf = ch & 1;
                    async16(kbp + (size_t)(s1 + nt * 16 + lr) * 1024 + hf * 32 + lq * 8,
                            Ks[nxt] + ch * 512);
                } else {
                    int dt = (ch - 8) >> 1, hf = ch & 1;
                    async16(vtb + (size_t)(dt * 16 + lr) * 2048 + s1 + hf * 32 + lq * 8,
                            Vs[nxt] + (ch - 8) * 512);
                }
            }
        }
        int s0 = kt * 64;

        floatx4 sacc[4];
#pragma unroll
        for (int nt = 0; nt < 4; nt++) sacc[nt] = zero;
#pragma unroll
        for (int nt = 0; nt < 4; nt++) {
            short8 b0 = *(const short8*)(Ks[cur] + nt * 1024 + c * 32 + quad * 8);
            short8 b1 = *(const short8*)(Ks[cur] + nt * 1024 + 512 + c * 32 + quad * 8);
            sacc[nt] = __builtin_amdgcn_mfma_f32_16x16x32_bf16(aq0, b0, sacc[nt], 0, 0, 0);
            sacc[nt] = __builtin_amdgcn_mfma_f32_16x16x32_bf16(aq1, b1, sacc[nt], 0, 0, 0);
        }

        if (kt == ntile - 1) {   // diagonal tile: causal mask
#pragma unroll
            for (int r = 0; r < 4; r++) {
                int t = t0w + quad * 4 + r;
                int row = w * 16 + quad * 4 + r;
                int swz = ((quad * 4 + r) & 7) << 3;
                float ps = 0.f;
#pragma unroll
                for (int nt = 0; nt < 4; nt++) {
                    float v = (s0 + nt * 16 + c > t) ? NEG_BIG : sacc[nt][r];
                    float e = __expf(v);
                    ps += e;
                    Ps[(row * 64 + nt * 16 + c) ^ swz] = f2bf_trunc(e);
                }
                l_part[r] += ps;
            }
        } else {
#pragma unroll
            for (int r = 0; r < 4; r++) {
                int row = w * 16 + quad * 4 + r;
                int swz = ((quad * 4 + r) & 7) << 3;
                float ps = 0.f;
#pragma unroll
                for (int nt = 0; nt < 4; nt++) {
                    float e = __expf(sacc[nt][r]);
                    ps += e;
                    Ps[(row * 64 + nt * 16 + c) ^ swz] = f2bf_trunc(e);
                }
                l_part[r] += ps;
            }
        }

        int prow = w * 16 + c;
        int pswz = (c & 7) << 3;
        short8 pa0 = *(const short8*)(Ps + ((prow * 64 + quad * 8) ^ pswz));
        short8 pa1 = *(const short8*)(Ps + ((prow * 64 + 32 + quad * 8) ^ pswz));
#pragma unroll
        for (int dt = 0; dt < 4; dt++) {
            short8 v0 = *(const short8*)(Vs[cur] + dt * 1024 + c * 32 + quad * 8);
            short8 v1 = *(const short8*)(Vs[cur] + dt * 1024 + 512 + c * 32 + quad * 8);
            oacc[dt] = __builtin_amdgcn_mfma_f32_16x16x32_bf16(pa0, v0, oacc[dt], 0, 0, 0);
            oacc[dt] = __builtin_amdgcn_mfma_f32_16x16x32_bf16(pa1, v1, oacc[dt], 0, 0, 0);
        }
    }

    float linv[4];
#pragma unroll
    for (int r = 0; r < 4; r++) {
        float l = l_part[r];
#pragma unroll
        for (int off = 1; off < 16; off <<= 1) l += __shfl_xor(l, off);
        linv[r] = 1.0f / l;
    }
#pragma unroll
    for (int dt = 0; dt < 4; dt++)
#pragma unroll
        for (int r = 0; r < 4; r++) {
            int t = t0w + quad * 4 + r;
            ob[(size_t)t * 1024 + dt * 16 + c] = f2bf_trunc(oacc[dt][r] * linv[r]);
        }
}

// ------------------------------------------------------------------ launch ---
extern "C" void kernel_launch(void* const* d_in, const int* in_sizes, int n_in,
                              void* d_out, int out_size, void* d_ws, size_t ws_size,
                              hipStream_t stream) {
    const ushort_t* x  = (const ushort_t*)d_in[0];
    const ushort_t* g  = (const ushort_t*)d_in[1];
    const ushort_t* Wq = (const ushort_t*)d_in[2];
    const ushort_t* Wk = (const ushort_t*)d_in[3];
    const ushort_t* Wv = (const ushort_t*)d_in[4];
    const ushort_t* Wo = (const ushort_t*)d_in[5];

    char* ws = (char*)d_ws;
    const size_t MB = 1ull << 20;
    ushort_t* xn   = (ushort_t*)(ws);            // 8 MB (reused as attn out)
    ushort_t* qb   = (ushort_t*)(ws + 8 * MB);   // 8 MB
    ushort_t* kb   = (ushort_t*)(ws + 16 * MB);  // 8 MB
    ushort_t* vt   = (ushort_t*)(ws + 24 * MB);  // 8 MB ([b,h,dh,s])
    ushort_t* WTq3 = (ushort_t*)(ws + 32 * MB);  // 6 MB (q|k|v transposed)
    ushort_t* WoT  = (ushort_t*)(ws + 38 * MB);  // 2 MB  -> total 40 MB
    ushort_t* at   = xn;

    prep_kernel<<<dim3(32, 32, 8), dim3(32, 8), 0, stream>>>(Wq, Wk, Wv, Wo, WTq3, WoT, x, g, xn);

    gemm_qkv<<<dim3(24, 32), 256, 0, stream>>>(xn, WTq3, qb, kb, vt);

    attn_kernel<<<dim3(32, 32), 256, 0, stream>>>(qb, kb, vt, at);

    gemm_out<<<dim3(16, 32), 256, 0, stream>>>(at, WoT, (float*)d_out);
}

// Round 4
// 183.304 us; speedup vs baseline: 1.1255x; 1.0139x over previous
//
#include <hip/hip_runtime.h>

typedef unsigned short ushort_t;
typedef __attribute__((ext_vector_type(8))) short short8;   // 8 bf16 (4 VGPRs)
typedef __attribute__((ext_vector_type(4))) short short4v;  // 4 bf16 (8 B)
typedef __attribute__((ext_vector_type(4))) float floatx4;  // 4 fp32 acc

#define DEV static __device__ __forceinline__
#define NEG_BIG (-1e30f)

typedef const __attribute__((address_space(1))) unsigned int* gas_ptr;
typedef __attribute__((address_space(3))) unsigned int* las_ptr;

// async global->LDS, 16B per lane; LDS dest = base + lane*16 (wave-uniform base)
DEV void async16(const ushort_t* g, ushort_t* l) {
    __builtin_amdgcn_global_load_lds((gas_ptr)(const void*)g, (las_ptr)(void*)l, 16, 0, 0);
}

DEV float bf2f(ushort_t u) {
    union { unsigned u; float f; } v; v.u = ((unsigned)u) << 16; return v.f;
}
DEV ushort_t f2bf(float f) {            // RNE — for values feeding long chains
    union { float f; unsigned u; } v; v.f = f;
    unsigned r = v.u + 0x7FFF + ((v.u >> 16) & 1);
    return (ushort_t)(r >> 16);
}
DEV ushort_t f2bf_trunc(float f) {      // 1-op truncation — P / O only (R13)
    union { float f; unsigned u; } v; v.f = f;
    return (ushort_t)(v.u >> 16);
}
DEV float load_bf16_scrub(const ushort_t* p, size_t i) {
    ushort_t u = p[i];
    if (((u >> 7) & 0xFF) == 0xFF) u = 0;
    return bf2f(u);
}
DEV float load_f32_scrub(const ushort_t* p, size_t i) {
    unsigned u = ((const unsigned*)p)[i];
    if (((u >> 23) & 0xFF) == 0xFF) u = 0;
    union { unsigned u; float f; } v; v.u = u; return v.f;
}

// Probe: fp32 vs bf16 raw data (proven in R3/R4). Block-uniform result.
DEV int probe_is_f32(const ushort_t* __restrict__ p) {
    int tid = threadIdx.x + threadIdx.y * blockDim.x;
    int nthr = blockDim.x * blockDim.y;
    __shared__ int cnt;
    if (tid == 0) cnt = 0;
    __syncthreads();
    int weird = 0;
    for (int i = tid; i < 2048; i += nthr) {
        unsigned e = (p[i] >> 7) & 0xFF;
        weird += (e >= 0x90) ? 1 : 0;
    }
#pragma unroll
    for (int off = 32; off; off >>= 1) weird += __shfl_xor(weird, off);
    if ((tid & 63) == 0) atomicAdd(&cnt, weird);
    __syncthreads();
    return cnt > 16;
}

// ----------------------------------------------- fused prep (1 launch) ------
__global__ void prep_kernel(const ushort_t* __restrict__ W0,
                            const ushort_t* __restrict__ W1,
                            const ushort_t* __restrict__ W2,
                            const ushort_t* __restrict__ W3,
                            ushort_t* __restrict__ WTq3,
                            ushort_t* __restrict__ WoT,
                            const ushort_t* __restrict__ x,
                            const ushort_t* __restrict__ g,
                            ushort_t* __restrict__ xn) {
    int is_f32 = probe_is_f32(x);
    int z = blockIdx.z;
    if (z < 4) {
        const ushort_t* W = (z == 0) ? W0 : (z == 1) ? W1 : (z == 2) ? W2 : W3;
        __shared__ ushort_t tile[32][33];
        int tx = threadIdx.x, ty = threadIdx.y;
        int xx = blockIdx.x * 32 + tx;      // n
        int y0 = blockIdx.y * 32;           // k
#pragma unroll
        for (int j = 0; j < 32; j += 8) {
            size_t idx = (size_t)(y0 + ty + j) * 1024 + xx;
            tile[ty + j][tx] = f2bf(is_f32 ? load_f32_scrub(W, idx) : load_bf16_scrub(W, idx));
        }
        __syncthreads();
        int nx = blockIdx.y * 32 + tx;
        ushort_t* dst = (z < 3) ? WTq3 : WoT;
        int ny0 = blockIdx.x * 32 + ((z < 3) ? z * 1024 : 0);
#pragma unroll
        for (int j = 0; j < 32; j += 8)
            dst[(size_t)(ny0 + ty + j) * 1024 + nx] = tile[tx][ty + j];
    } else {
        int row = (z - 4) * 1024 + blockIdx.y * 32 + blockIdx.x;
        int tid = threadIdx.y * 32 + threadIdx.x;
        float vals[4], gv[4];
        size_t base = (size_t)row * 1024 + tid * 4;
#pragma unroll
        for (int i = 0; i < 4; i++) {
            if (is_f32) {
                vals[i] = load_f32_scrub(x, base + i);
                gv[i]   = load_f32_scrub(g, tid * 4 + i);
            } else {
                vals[i] = load_bf16_scrub(x, base + i);
                gv[i]   = load_bf16_scrub(g, tid * 4 + i);
            }
        }
        float ss = vals[0]*vals[0] + vals[1]*vals[1] + vals[2]*vals[2] + vals[3]*vals[3];
#pragma unroll
        for (int off = 32; off > 0; off >>= 1) ss += __shfl_xor(ss, off);
        __shared__ float red[4];
        if ((tid & 63) == 0) red[tid >> 6] = ss;
        __syncthreads();
        ss = red[0] + red[1] + red[2] + red[3];
        float inv = rsqrtf(ss * (1.0f / 1024.0f) + 1e-6f);
#pragma unroll
        for (int i = 0; i < 4; i++)
            xn[base + i] = f2bf(vals[i] * inv * gv[i]);
    }
}

// ------------------------------------------------------- fused QKV GEMM ----
// 128x128 tile, BK=64, COALESCED async staging (R8/R10-verified; R9 proved
// bank conflicts benign / coalescing binding). XCD-region swizzle.
// Epilogue: fast-math RoPE (__sinf/__cosf), q pre-scaled 1/8, packed V scatter.
__global__ __launch_bounds__(256, 4) void gemm_qkv(const ushort_t* __restrict__ A,
                                                   const ushort_t* __restrict__ Bt,
                                                   ushort_t* __restrict__ qb,
                                                   ushort_t* __restrict__ kb,
                                                   ushort_t* __restrict__ vt) {
    const int K = 1024;
    int tid = threadIdx.x;
    int lane = tid & 63, w = tid >> 6;
    int c = lane & 15, quad = lane >> 4;
    int mh = w >> 1, nh = w & 1;
    int lin = blockIdx.y * gridDim.x + blockIdx.x;     // 768 blocks
    int xcd = lin & 7, idx = lin >> 3;
    int bm = ((xcd & 3) * 8 + (idx & 7)) * 128;        // m-block in [0,32)
    int bn = ((xcd >> 2) * 12 + (idx >> 3)) * 128;     // n-block in [0,24)
    int lr = lane >> 2, lq = lane & 3;                 // staging lane map

    __shared__ __align__(16) ushort_t As[16 * 512];    // 16 KB
    __shared__ __align__(16) ushort_t Bs[16 * 512];    // 16 KB

    const floatx4 zero = {0.f, 0.f, 0.f, 0.f};
    floatx4 acc[4][4];
#pragma unroll
    for (int i = 0; i < 4; i++)
#pragma unroll
        for (int j = 0; j < 4; j++) acc[i][j] = zero;

    for (int k0 = 0; k0 < K; k0 += 64) {
        __syncthreads();
#pragma unroll
        for (int ci = 0; ci < 8; ci++) {
            int ch = w * 8 + ci;              // 0..31, wave-uniform
            if (ch < 16) {
                int rg = ch >> 1, kc = ch & 1;
                async16(A + (size_t)(bm + rg * 16 + lr) * K + k0 + kc * 32 + lq * 8,
                        As + ch * 512);
            } else {
                int b2 = ch - 16;
                int rg = b2 >> 1, kc = b2 & 1;
                async16(Bt + (size_t)(bn + rg * 16 + lr) * K + k0 + kc * 32 + lq * 8,
                        Bs + b2 * 512);
            }
        }
        __syncthreads();
#pragma unroll
        for (int kc = 0; kc < 2; kc++) {
            short8 af[4], bf[4];
#pragma unroll
            for (int i = 0; i < 4; i++)
                af[i] = *(const short8*)(As + ((mh * 4 + i) * 2 + kc) * 512 + c * 32 + quad * 8);
#pragma unroll
            for (int j = 0; j < 4; j++)
                bf[j] = *(const short8*)(Bs + ((nh * 4 + j) * 2 + kc) * 512 + c * 32 + quad * 8);
#pragma unroll
            for (int i = 0; i < 4; i++)
#pragma unroll
                for (int j = 0; j < 4; j++)
                    acc[i][j] = __builtin_amdgcn_mfma_f32_16x16x32_bf16(af[i], bf[j], acc[i][j], 0, 0, 0);
        }
    }

    int proj = bn >> 10;                 // 0=q, 1=k, 2=v (blocks never straddle)
    int n0 = (bn & 1023) + nh * 64;
    if (proj < 2) {                      // RoPE: d = j*16+c, pairs (j, j+2)
        float th0 = exp2f((float)c * (-19.931568569324174f / 32.0f));
        float th1 = exp2f((float)(16 + c) * (-19.931568569324174f / 32.0f));
        float scale = (proj == 0) ? 0.125f : 1.0f;
#pragma unroll
        for (int i = 0; i < 4; i++)
#pragma unroll
            for (int r = 0; r < 4; r++) {
                int s = (bm + mh * 64 + i * 16 + quad * 4 + r) & 2047;
                float a0 = (float)s * th0, a1 = (float)s * th1;
                float sn0 = __sinf(a0), cs0 = __cosf(a0);
                float sn1 = __sinf(a1), cs1 = __cosf(a1);
                float x1a = acc[i][0][r], x2a = acc[i][2][r];
                acc[i][0][r] = (x1a * cs0 - x2a * sn0) * scale;
                acc[i][2][r] = (x1a * sn0 + x2a * cs0) * scale;
                float x1b = acc[i][1][r], x2b = acc[i][3][r];
                acc[i][1][r] = (x1b * cs1 - x2b * sn1) * scale;
                acc[i][3][r] = (x1b * sn1 + x2b * cs1) * scale;
            }
        ushort_t* dst = (proj == 0) ? qb : kb;
#pragma unroll
        for (int i = 0; i < 4; i++)
#pragma unroll
            for (int j = 0; j < 4; j++)
#pragma unroll
                for (int r = 0; r < 4; r++) {
                    int row = bm + mh * 64 + i * 16 + quad * 4 + r;
                    dst[(size_t)row * 1024 + n0 + j * 16 + c] = f2bf(acc[i][j][r]);
                }
    } else {                             // V: packed 8-B scatter (4 consecutive s)
#pragma unroll
        for (int i = 0; i < 4; i++) {
            int row0 = bm + mh * 64 + i * 16 + quad * 4;
            int b = row0 >> 11, s0v = row0 & 2047;
#pragma unroll
            for (int j = 0; j < 4; j++) {
                int col = n0 + j * 16 + c;
                int hh = col >> 6, dh = col & 63;
                short4v pk;
#pragma unroll
                for (int r = 0; r < 4; r++) pk[r] = (short)f2bf(acc[i][j][r]);
                *(short4v*)(vt + (size_t)((b * 16 + hh) * 64 + dh) * 2048 + s0v) = pk;
            }
        }
    }
}

// ----------------------------------------------------- output projection ---
__global__ __launch_bounds__(256, 4) void gemm_out(const ushort_t* __restrict__ A,
                                                   const ushort_t* __restrict__ Bt,
                                                   float* __restrict__ C) {
    const int K = 1024, N = 1024;
    int tid = threadIdx.x;
    int lane = tid & 63, w = tid >> 6;
    int c = lane & 15, quad = lane >> 4;
    int mh = w >> 1, nh = w & 1;
    int lin = blockIdx.y * gridDim.x + blockIdx.x;     // 512 blocks
    int xcd = lin & 7, idx = lin >> 3;
    int bm = ((xcd & 3) * 8 + (idx & 7)) * 128;
    int bn = ((xcd >> 2) * 8 + (idx >> 3)) * 64;
    int lr = lane >> 2, lq = lane & 3;

    __shared__ __align__(16) ushort_t As[16 * 512];
    __shared__ __align__(16) ushort_t Bs[8 * 512];

    const floatx4 zero = {0.f, 0.f, 0.f, 0.f};
    floatx4 acc[4][2];
#pragma unroll
    for (int i = 0; i < 4; i++)
#pragma unroll
        for (int j = 0; j < 2; j++) acc[i][j] = zero;

    for (int k0 = 0; k0 < K; k0 += 64) {
        __syncthreads();
#pragma unroll
        for (int ci = 0; ci < 6; ci++) {
            int ch = w * 6 + ci;              // 0..23, wave-uniform
            if (ch < 16) {
                int rg = ch >> 1, kc = ch & 1;
                async16(A + (size_t)(bm + rg * 16 + lr) * K + k0 + kc * 32 + lq * 8,
                        As + ch * 512);
            } else {
                int b2 = ch - 16;
                int rg = b2 >> 1, kc = b2 & 1;
                async16(Bt + (size_t)(bn + rg * 16 + lr) * K + k0 + kc * 32 + lq * 8,
                        Bs + b2 * 512);
            }
        }
        __syncthreads();
#pragma unroll
        for (int kc = 0; kc < 2; kc++) {
            short8 af[4], bf[2];
#pragma unroll
            for (int i = 0; i < 4; i++)
                af[i] = *(const short8*)(As + ((mh * 4 + i) * 2 + kc) * 512 + c * 32 + quad * 8);
#pragma unroll
            for (int j = 0; j < 2; j++)
                bf[j] = *(const short8*)(Bs + ((nh * 2 + j) * 2 + kc) * 512 + c * 32 + quad * 8);
#pragma unroll
            for (int i = 0; i < 4; i++)
#pragma unroll
                for (int j = 0; j < 2; j++)
                    acc[i][j] = __builtin_amdgcn_mfma_f32_16x16x32_bf16(af[i], bf[j], acc[i][j], 0, 0, 0);
        }
    }
#pragma unroll
    for (int i = 0; i < 4; i++)
#pragma unroll
        for (int j = 0; j < 2; j++)
#pragma unroll
            for (int r = 0; r < 4; r++) {
                int row = bm + mh * 64 + i * 16 + quad * 4 + r;
                int col = bn + nh * 32 + j * 16 + c;
                C[(size_t)row * N + col] = acc[i][j][r];
            }
}

// -------------------------------------------------------------- attention ---
// R17: swapped QK^T (R15's verified mapping: mfma(K,Q) -> lane (c,quad) holds
// S[t=t0w+c][s=s0+nt*16+quad*4+r]) + full-rate x32 PV (R13's) joined by a
// b64-write / b128-read P buffer:
//   write: lane packs 4 consecutive s into short4v -> ONE ds_write_b64 per nt
//          (4 writes/tile vs R13's 16 scalar b16 writes)
//   read:  standard x32 A-frag, 2x ds_read_b128 (lane supplies P[row c][s=quad*8+e])
//   layout: Ps[64][64] with byte-addr ^ ((c&7)<<4) (row-bijective XOR, applied
//          on BOTH sides). Write chunk (nt,quad>>1) lands at slot nt*2+(quad>>1)
//          == read slot quad / 4+quad — verified contiguous 16B per read.
// V staged/read exactly as R13 (no rotation — R15's conflict source removed).
// LDS: 16K K-dbuf + 16K V-dbuf + 8K Ps = 40960 B.
__global__ __launch_bounds__(256) void attn_kernel(const ushort_t* __restrict__ q,
                                                   const ushort_t* __restrict__ k,
                                                   const ushort_t* __restrict__ vt,
                                                   ushort_t* __restrict__ o) {
    int tid = threadIdx.x;
    int lane = tid & 63, w = tid >> 6;
    int c = lane & 15, quad = lane >> 4;
    int bh = blockIdx.x;
    int b = bh >> 4, h = bh & 15;
    int qt = 31 - (int)blockIdx.y;      // heaviest (qt=31) first
    int lr = lane >> 2, lq = lane & 3;
    const ushort_t* qb  = q + (size_t)b * 2048 * 1024 + h * 64;
    const ushort_t* kbp = k + (size_t)b * 2048 * 1024 + h * 64;
    const ushort_t* vtb = vt + (size_t)(b * 16 + h) * 64 * 2048;
    ushort_t* ob = o + (size_t)b * 2048 * 1024 + h * 64;

    __shared__ __align__(16) ushort_t Ks[2][8 * 512];   // 16 KB
    __shared__ __align__(16) ushort_t Vs[2][8 * 512];   // 16 KB
    __shared__ __align__(16) ushort_t Ps[64 * 64];      // 8 KB, XOR-swizzled

    const floatx4 zero = {0.f, 0.f, 0.f, 0.f};

    int t0b = qt * 64;
    int t0w = t0b + w * 16;
    int ntile = qt + 1;

    // Q rows for this wave; used as the MFMA B operand (B-frag n=lane&15=c ->
    // q-row t0w+c, k=quad*8+e -> d — same registers/loads as R13).
    const ushort_t* qrow = qb + (size_t)(t0w + c) * 1024;
    short8 aq0 = *(const short8*)(qrow + quad * 8);
    short8 aq1 = *(const short8*)(qrow + 32 + quad * 8);

    // P LDS addressing (shorts). Row = w*16 + c; row-bijective XOR (c&7)<<3.
    int pswz = (c & 7) << 3;
    int pwbase = ((w * 16 + c) * 64) ;                  // + nt*16 + quad*4, ^pswz
    int prbase = ((w * 16 + c) * 64) ;                  // + quad*8 (+32), ^pswz

    float l_sum = 0.f;
    floatx4 oacc[4];
#pragma unroll
    for (int dt = 0; dt < 4; dt++) oacc[dt] = zero;

    // prologue: stage tile 0 into buffer 0
#pragma unroll
    for (int ci = 0; ci < 4; ci++) {
        int ch = w * 4 + ci;
        if (ch < 8) {
            int nt = ch >> 1, hf = ch & 1;
            async16(kbp + (size_t)(nt * 16 + lr) * 1024 + hf * 32 + lq * 8,
                    Ks[0] + ch * 512);
        } else {
            int dt = (ch - 8) >> 1, hf = ch & 1;
            async16(vtb + (size_t)(dt * 16 + lr) * 2048 + hf * 32 + lq * 8,
                    Vs[0] + (ch - 8) * 512);
        }
    }

    for (int kt = 0; kt < ntile; kt++) {
        __syncthreads();    // drains tile kt's loads
        int cur = kt & 1;
        if (kt + 1 < ntile) {
            int s1 = (kt + 1) * 64;
            int nxt = cur ^ 1;
#pragma unroll
            for (int ci = 0; ci < 4; ci++) {
                int ch = w * 4 + ci;
                if (ch < 8) {
                    int nt = ch >> 1, hf = ch & 1;
                    async16(kbp + (size_t)(s1 + nt * 16 + lr) * 1024 + hf * 32 + lq * 8,
                            Ks[nxt] + ch * 512);
                } else {
                    int dt = (ch - 8) >> 1, hf = ch & 1;
                    async16(vtb + (size_t)(dt * 16 + lr) * 2048 + s1 + hf * 32 + lq * 8,
                            Vs[nxt] + (ch - 8) * 512);
                }
            }
        }
        int s0 = kt * 64;

        // ---- QK^T swapped: A = K rows (m=c -> s), B = Q regs (n=c -> t).
        // sacc[nt][r] = S[t0w + c][s0 + nt*16 + quad*4 + r]
        floatx4 sacc[4];
#pragma unroll
        for (int nt = 0; nt < 4; nt++) sacc[nt] = zero;
#pragma unroll
        for (int nt = 0; nt < 4; nt++) {
            short8 k0f = *(const short8*)(Ks[cur] + nt * 1024 + c * 32 + quad * 8);
            short8 k1f = *(const short8*)(Ks[cur] + nt * 1024 + 512 + c * 32 + quad * 8);
            sacc[nt] = __builtin_amdgcn_mfma_f32_16x16x32_bf16(k0f, aq0, sacc[nt], 0, 0, 0);
            sacc[nt] = __builtin_amdgcn_mfma_f32_16x16x32_bf16(k1f, aq1, sacc[nt], 0, 0, 0);
        }

        // ---- softmax: whole 4-run of s is lane-local -> pack + ONE b64 write/nt
        if (kt == ntile - 1) {           // diagonal tile: causal mask
            int t = t0w + c;
#pragma unroll
            for (int nt = 0; nt < 4; nt++) {
                short4v pk;
                float pn = 0.f;
#pragma unroll
                for (int r = 0; r < 4; r++) {
                    int s = s0 + nt * 16 + quad * 4 + r;
                    float e = __expf((s > t) ? NEG_BIG : sacc[nt][r]);
                    pn += e;
                    pk[r] = (short)f2bf_trunc(e);
                }
                l_sum += pn;
                *(short4v*)(Ps + ((pwbase + nt * 16 + quad * 4) ^ pswz)) = pk;
            }
        } else {
#pragma unroll
            for (int nt = 0; nt < 4; nt++) {
                short4v pk;
                float pn = 0.f;
#pragma unroll
                for (int r = 0; r < 4; r++) {
                    float e = __expf(sacc[nt][r]);
                    pn += e;
                    pk[r] = (short)f2bf_trunc(e);
                }
                l_sum += pn;
                *(short4v*)(Ps + ((pwbase + nt * 16 + quad * 4) ^ pswz)) = pk;
            }
        }

        // ---- PV: A = P from LDS (m=c -> t, k=quad*8+e -> s), B = V^T (R13)
        short8 pa0 = *(const short8*)(Ps + ((prbase + quad * 8) ^ pswz));
        short8 pa1 = *(const short8*)(Ps + ((prbase + 32 + quad * 8) ^ pswz));
#pragma unroll
        for (int dt = 0; dt < 4; dt++) {
            short8 v0 = *(const short8*)(Vs[cur] + dt * 1024 + c * 32 + quad * 8);
            short8 v1 = *(const short8*)(Vs[cur] + dt * 1024 + 512 + c * 32 + quad * 8);
            oacc[dt] = __builtin_amdgcn_mfma_f32_16x16x32_bf16(pa0, v0, oacc[dt], 0, 0, 0);
            oacc[dt] = __builtin_amdgcn_mfma_f32_16x16x32_bf16(pa1, v1, oacc[dt], 0, 0, 0);
        }
    }

    // l_sum is the quad-partial row sum for q-row t0w + c -> reduce over quads
    float l = l_sum;
    l += __shfl_xor(l, 16);
    l += __shfl_xor(l, 32);
    float linv0 = 1.0f / l;              // valid for row t0w + c
    float linv[4];
#pragma unroll
    for (int r = 0; r < 4; r++) linv[r] = __shfl(linv0, quad * 4 + r);

#pragma unroll
    for (int dt = 0; dt < 4; dt++)
#pragma unroll
        for (int r = 0; r < 4; r++) {
            int t = t0w + quad * 4 + r;
            ob[(size_t)t * 1024 + dt * 16 + c] = f2bf_trunc(oacc[dt][r] * linv[r]);
        }
}

// ------------------------------------------------------------------ launch ---
extern "C" void kernel_launch(void* const* d_in, const int* in_sizes, int n_in,
                              void* d_out, int out_size, void* d_ws, size_t ws_size,
                              hipStream_t stream) {
    const ushort_t* x  = (const ushort_t*)d_in[0];
    const ushort_t* g  = (const ushort_t*)d_in[1];
    const ushort_t* Wq = (const ushort_t*)d_in[2];
    const ushort_t* Wk = (const ushort_t*)d_in[3];
    const ushort_t* Wv = (const ushort_t*)d_in[4];
    const ushort_t* Wo = (const ushort_t*)d_in[5];

    char* ws = (char*)d_ws;
    const size_t MB = 1ull << 20;
    ushort_t* xn   = (ushort_t*)(ws);            // 8 MB (reused as attn out)
    ushort_t* qb   = (ushort_t*)(ws + 8 * MB);   // 8 MB
    ushort_t* kb   = (ushort_t*)(ws + 16 * MB);  // 8 MB
    ushort_t* vt   = (ushort_t*)(ws + 24 * MB);  // 8 MB ([b,h,dh,s])
    ushort_t* WTq3 = (ushort_t*)(ws + 32 * MB);  // 6 MB (q|k|v transposed)
    ushort_t* WoT  = (ushort_t*)(ws + 38 * MB);  // 2 MB  -> total 40 MB
    ushort_t* at   = xn;

    prep_kernel<<<dim3(32, 32, 8), dim3(32, 8), 0, stream>>>(Wq, Wk, Wv, Wo, WTq3, WoT, x, g, xn);

    gemm_qkv<<<dim3(24, 32), 256, 0, stream>>>(xn, WTq3, qb, kb, vt);

    attn_kernel<<<dim3(32, 32), 256, 0, stream>>>(qb, kb, vt, at);

    gemm_out<<<dim3(16, 32), 256, 0, stream>>>(at, WoT, (float*)d_out);
}